// Round 17
// baseline (124.576 us; speedup 1.0000x reference)
//
#include <hip/hip_runtime.h>
#include <math.h>

#define NPIX 50176      // 16*56*56
#define CDIM 384
#define HEADS 6
#define NLOGIT 54       // HEADS*9
#define HH 56
#define WW 56
#define KSTEPS 12       // CDIM/32
#define NCH_V 28        // total fragment chunks (448 cols / 16)
#define NCH_P 24        // proj fragment chunks (384 cols / 16)

typedef __attribute__((ext_vector_type(8))) __bf16 bf16x8;
typedef __attribute__((ext_vector_type(4))) float f32x4;

__device__ __forceinline__ void glds16(const void* g, void* l) {
  __builtin_amdgcn_global_load_lds(
      (const __attribute__((address_space(1))) unsigned int*)g,
      (__attribute__((address_space(3))) unsigned int*)l, 16, 0, 0);
}

// ---------------------------------------------------------------------------
// Prep: fragment-major weights (unchanged, proven).
// ---------------------------------------------------------------------------
__global__ __launch_bounds__(256) void prep_kernel(
    const float* __restrict__ W_v, const float* __restrict__ W_proj,
    const float* __restrict__ W_attn, const float* __restrict__ b_attn,
    __bf16* __restrict__ Wcat_frag, __bf16* __restrict__ Wtp_frag,
    float* __restrict__ bpad) {
  const int gid = blockIdx.x * 256 + threadIdx.x;
  const int NV = KSTEPS * NCH_V * 64;   // 21504
  const int NP = KSTEPS * NCH_P * 64;   // 18432
  if (gid < NV) {
    const int ks   = gid / (NCH_V * 64);
    const int rem  = gid % (NCH_V * 64);
    const int ni   = rem >> 6;
    const int lane = rem & 63;
    const int n  = ni * 16 + (lane & 15);
    const int kb = ks * 32 + (lane >> 4) * 8;
    bf16x8 o;
    #pragma unroll
    for (int q = 0; q < 8; ++q) {
      const int k = kb + q;
      float val;
      if (n < CDIM) val = W_v[k * CDIM + n];
      else {
        const int nn = n - CDIM;
        val = (nn < NLOGIT) ? W_attn[k * NLOGIT + nn] : 0.f;
      }
      o[q] = (__bf16)val;
    }
    *(bf16x8*)&Wcat_frag[(size_t)gid * 8] = o;
  } else if (gid < NV + NP) {
    const int r    = gid - NV;
    const int ks   = r / (NCH_P * 64);
    const int rem  = r % (NCH_P * 64);
    const int ni   = rem >> 6;
    const int lane = rem & 63;
    const int n  = ni * 16 + (lane & 15);
    const int kb = ks * 32 + (lane >> 4) * 8;
    bf16x8 o;
    #pragma unroll
    for (int q = 0; q < 8; ++q) o[q] = (__bf16)W_proj[(kb + q) * CDIM + n];
    *(bf16x8*)&Wtp_frag[(size_t)r * 8] = o;
  } else if (gid < NV + NP + 64) {
    const int n = gid - NV - NP;
    bpad[n] = (n < NLOGIT) ? b_attn[n] : 0.f;
  }
}

// ---------------------------------------------------------------------------
// Cast x fp32 -> bf16, 16 elements / thread. Pure streaming (~19us).
// ---------------------------------------------------------------------------
__global__ __launch_bounds__(256) void cast_x_kernel(
    const float* __restrict__ x, __bf16* __restrict__ xb) {
  const size_t i = (size_t)blockIdx.x * 256 + threadIdx.x;
  const float4* src = (const float4*)x + i * 4;
  const float4 f0 = src[0];
  const float4 f1 = src[1];
  const float4 f2 = src[2];
  const float4 f3 = src[3];
  bf16x8 o0, o1;
  o0[0] = (__bf16)f0.x; o0[1] = (__bf16)f0.y; o0[2] = (__bf16)f0.z; o0[3] = (__bf16)f0.w;
  o0[4] = (__bf16)f1.x; o0[5] = (__bf16)f1.y; o0[6] = (__bf16)f1.z; o0[7] = (__bf16)f1.w;
  o1[0] = (__bf16)f2.x; o1[1] = (__bf16)f2.y; o1[2] = (__bf16)f2.z; o1[3] = (__bf16)f2.w;
  o1[4] = (__bf16)f3.x; o1[5] = (__bf16)f3.y; o1[6] = (__bf16)f3.z; o1[7] = (__bf16)f3.w;
  ((bf16x8*)xb)[i * 2]     = o0;
  ((bf16x8*)xb)[i * 2 + 1] = o1;
}

// ---------------------------------------------------------------------------
// GEMM body — r13/r16-proven schedule: plain __syncthreads double-buffer,
// A per-lane bf16x8 from global (1-step prefetch), B fragment-major glds16.
// ---------------------------------------------------------------------------
template <int NCH, int STRIDE, int NBASE, bool LOGIT, bool F32OUT>
__device__ __forceinline__ void gemm_body(
    const __bf16* __restrict__ A, const __bf16* __restrict__ Wf,
    const float* __restrict__ bias, void* __restrict__ out,
    const float* __restrict__ bpad, float* __restrict__ attn,
    __bf16* Bs, int bm, int tid) {
  constexpr int CPW = NCH / 4;          // chunks per wave
  const int wave = tid >> 6;
  const int lane = tid & 63;
  const int frow = lane & 15;
  const int fk8  = (lane >> 4) * 8;
  const int arow = bm + wave * 16 + frow;
  const __bf16* xrow = A + (size_t)arow * CDIM + fk8;

  f32x4 acc[NCH] = {};

  // prologue: stage(0) -> buf0, load A(0)
  #pragma unroll
  for (int c = 0; c < CPW; ++c) {
    const int chunk = wave * CPW + c;
    glds16(Wf + ((size_t)(NBASE + chunk) * 64 + lane) * 8, Bs + chunk * 512);
  }
  bf16x8 a = *(const bf16x8*)xrow;
  __syncthreads();

  int buf = 0;
  for (int ks = 0; ks < KSTEPS; ++ks) {
    if (ks + 1 < KSTEPS) {
      __bf16* dst = Bs + (buf ^ 1) * NCH * 512;
      #pragma unroll
      for (int c = 0; c < CPW; ++c) {
        const int chunk = wave * CPW + c;
        glds16(Wf + ((size_t)((ks + 1) * STRIDE + NBASE + chunk) * 64 + lane) * 8,
               dst + chunk * 512);
      }
    }
    bf16x8 a_next;
    if (ks + 1 < KSTEPS) a_next = *(const bf16x8*)(xrow + (ks + 1) * 32);

    const __bf16* Bc = Bs + buf * NCH * 512;
    #pragma unroll
    for (int ni = 0; ni < NCH; ++ni) {
      const bf16x8 b = *(const bf16x8*)&Bc[(ni * 64 + lane) * 8];
      acc[ni] = __builtin_amdgcn_mfma_f32_16x16x32_bf16(a, b, acc[ni], 0, 0, 0);
    }
    __syncthreads();
    buf ^= 1;
    a = a_next;
  }

  const int orow = (lane >> 4) * 4;
  constexpr int NV = LOGIT ? NCH - 4 : NCH;

  #pragma unroll
  for (int ni = 0; ni < NV; ++ni) {
    const int n = (NBASE + ni) * 16 + frow;
    const float bvl = bias[n];
    #pragma unroll
    for (int r = 0; r < 4; ++r) {
      const int m = bm + wave * 16 + orow + r;
      const float val = acc[ni][r] + bvl;
      if constexpr (F32OUT)
        ((float*)out)[(size_t)m * CDIM + n] = val;
      else
        ((__bf16*)out)[(size_t)m * CDIM + n] = (__bf16)val;
    }
  }

  if constexpr (LOGIT) {
    float (*Ls)[68] = (float(*)[68])Bs;
    __syncthreads();   // all waves done reading Bs before overlay
    float bvl[4];
    #pragma unroll
    for (int ni = 0; ni < 4; ++ni) bvl[ni] = bpad[ni * 16 + frow];
    #pragma unroll
    for (int ni = 0; ni < 4; ++ni)
      #pragma unroll
      for (int r = 0; r < 4; ++r)
        Ls[wave * 16 + orow + r][ni * 16 + frow] = acc[NV + ni][r] + bvl[ni];
    __syncthreads();

    #pragma unroll
    for (int it = 0; it < 2; ++it) {
      const int task = it * 256 + tid;
      if (task < 64 * HEADS) {
        const int pl = task / HEADS;
        const int h  = task % HEADS;
        const float* row = &Ls[pl][h * 9];
        float m = row[0];
        #pragma unroll
        for (int w = 1; w < 9; ++w) m = fmaxf(m, row[w]);
        float e[9], s = 0.f;
        #pragma unroll
        for (int w = 0; w < 9; ++w) { e[w] = __expf(row[w] - m); s += e[w]; }
        const float inv = 1.f / s;
        float* op = &attn[(size_t)(bm + pl) * NLOGIT + h * 9];
        #pragma unroll
        for (int w = 0; w < 9; ++w) op[w] = e[w] * inv;
      }
    }
  }
}

// ---------------------------------------------------------------------------
// Merged v + logit GEMM: grid (NPIX/64, 3) — all panels proj-shaped.
//   by=0: chunks 0..11  (v cols 0..191),   NCH=12
//   by=1: chunks 12..23 (v cols 192..383), NCH=12
//   by=2: chunks 24..27 (logit cols) -> softmax -> attn, NCH=4
// Light by=2 blocks co-schedule among heavy v blocks (latency hidden).
// ---------------------------------------------------------------------------
__global__ __launch_bounds__(256) void gemm_v_logit_kernel(
    const __bf16* __restrict__ xb, const __bf16* __restrict__ Wcat_frag,
    const float* __restrict__ b_v, __bf16* __restrict__ v,
    const float* __restrict__ bpad, float* __restrict__ attn) {
  __shared__ __bf16 Bs[2 * 12 * 512];   // 24KB (by=2 uses 8KB; Ls needs 17.4KB)
  const int bm = blockIdx.x * 64;
  if (blockIdx.y == 0)
    gemm_body<12, NCH_V, 0, false, false>(
        xb, Wcat_frag, b_v, v, bpad, attn, Bs, bm, threadIdx.x);
  else if (blockIdx.y == 1)
    gemm_body<12, NCH_V, 12, false, false>(
        xb, Wcat_frag, b_v, v, bpad, attn, Bs, bm, threadIdx.x);
  else
    gemm_body<4, NCH_V, 24, true, false>(
        xb, Wcat_frag, b_v, v, bpad, attn, Bs, bm, threadIdx.x);
}

// ---------------------------------------------------------------------------
// Proj GEMM: grid (NPIX/64, 2), 12 chunks each (unchanged, ~22us). Out fp32.
// ---------------------------------------------------------------------------
__global__ __launch_bounds__(256) void gemm_proj_kernel(
    const __bf16* __restrict__ Y, const __bf16* __restrict__ Wtp_frag,
    const float* __restrict__ bias, float* __restrict__ Out) {
  __shared__ __bf16 Bs[2 * 12 * 512];   // 24KB
  const int bm = blockIdx.x * 64;
  if (blockIdx.y == 0)
    gemm_body<12, NCH_P, 0, false, true>(
        Y, Wtp_frag, bias, Out, nullptr, nullptr, Bs, bm, threadIdx.x);
  else
    gemm_body<12, NCH_P, 12, false, true>(
        Y, Wtp_frag, bias, Out, nullptr, nullptr, Bs, bm, threadIdx.x);
}

// ---------------------------------------------------------------------------
// Window aggregation, 4 vertically-adjacent pixels per thread (unchanged).
// ---------------------------------------------------------------------------
__global__ __launch_bounds__(256) void aggregate_kernel(
    const __bf16* __restrict__ v, const float* __restrict__ attn,
    __bf16* __restrict__ y) {
  const int idx = blockIdx.x * 256 + threadIdx.x;  // NPIX/4 * 48 = 602112
  const int cg = idx % 48;
  const int pg = idx / 48;
  const int c  = cg * 8;
  const int b  = pg / ((HH / 4) * WW);
  const int r2 = pg % ((HH / 4) * WW);
  const int i0 = (r2 / WW) * 4;
  const int j  = r2 % WW;
  const int head = c >> 6;

  const int pbase = (b * HH + i0) * WW + j;
  float aw[4][9];
  #pragma unroll
  for (int p = 0; p < 4; ++p) {
    const float* ap = attn + (size_t)(pbase + p * WW) * NLOGIT + head * 9;
    #pragma unroll
    for (int w = 0; w < 9; ++w) aw[p][w] = ap[w];
  }

  const bool j0ok = (j > 0), j2ok = (j < WW - 1);
  float acc[4][8] = {};

  #pragma unroll
  for (int li = 0; li < 6; ++li) {
    const int ii = i0 - 1 + li;
    if (ii < 0 || ii >= HH) continue;
    const __bf16* vrow = v + ((size_t)(b * HH + ii) * WW + j) * CDIM + c;
    float ch[3][8];
    #pragma unroll
    for (int kj = 0; kj < 3; ++kj) {
      const bool ok = (kj == 0) ? j0ok : (kj == 2) ? j2ok : true;
      if (ok) {
        const bf16x8 vv = *(const bf16x8*)(vrow + (kj - 1) * CDIM);
        #pragma unroll
        for (int q = 0; q < 8; ++q) ch[kj][q] = (float)vv[q];
      } else {
        #pragma unroll
        for (int q = 0; q < 8; ++q) ch[kj][q] = 0.f;
      }
    }
    #pragma unroll
    for (int p = 0; p < 4; ++p) {
      const int ki = li - p;
      if (ki < 0 || ki > 2) continue;
      #pragma unroll
      for (int kj = 0; kj < 3; ++kj) {
        const float w = aw[p][ki * 3 + kj];
        #pragma unroll
        for (int q = 0; q < 8; ++q) acc[p][q] += w * ch[kj][q];
      }
    }
  }

  #pragma unroll
  for (int p = 0; p < 4; ++p) {
    bf16x8 o;
    #pragma unroll
    for (int q = 0; q < 8; ++q) o[q] = (__bf16)acc[p][q];
    *(bf16x8*)&y[(size_t)(pbase + p * WW) * CDIM + c] = o;
  }
}

// ---------------------------------------------------------------------------
extern "C" void kernel_launch(void* const* d_in, const int* in_sizes, int n_in,
                              void* d_out, int out_size, void* d_ws,
                              size_t ws_size, hipStream_t stream) {
  const float* x      = (const float*)d_in[0];
  const float* W_attn = (const float*)d_in[1];
  const float* b_attn = (const float*)d_in[2];
  const float* W_v    = (const float*)d_in[3];
  const float* b_v    = (const float*)d_in[4];
  const float* W_proj = (const float*)d_in[5];
  const float* b_proj = (const float*)d_in[6];
  float* out = (float*)d_out;

  char* w = (char*)d_ws;
  __bf16* xb   = (__bf16*)w;  w += (size_t)NPIX * CDIM * 2;   // 38.5MB
  __bf16* v    = (__bf16*)w;  w += (size_t)NPIX * CDIM * 2;   // 38.5MB
  __bf16* y    = (__bf16*)w;  w += (size_t)NPIX * CDIM * 2;   // 38.5MB
  float*  attn = (float*)w;   w += (size_t)NPIX * NLOGIT * 4; // 10.8MB
  __bf16* Wcat_frag = (__bf16*)w;  w += (size_t)(NCH_V * 16) * CDIM * 2;
  __bf16* Wtp_frag  = (__bf16*)w;  w += (size_t)CDIM * CDIM * 2;
  float*  bpad = (float*)w;   w += 64 * 4;

  // prep: fragment-major weights
  const int prep_n = KSTEPS * NCH_V * 64 + KSTEPS * NCH_P * 64 + 64;
  prep_kernel<<<(prep_n + 255) / 256, 256, 0, stream>>>(
      W_v, W_proj, W_attn, b_attn, Wcat_frag, Wtp_frag, bpad);

  // 0. x -> bf16 (streaming)
  cast_x_kernel<<<(NPIX * CDIM / 16) / 256, 256, 0, stream>>>(x, xb);

  // 1. merged v-GEMM + logits/softmax (3 proj-shaped panels)
  gemm_v_logit_kernel<<<dim3(NPIX / 64, 3), 256, 0, stream>>>(
      xb, Wcat_frag, b_v, v, bpad, attn);

  // 2. window aggregation -> y (bf16), 4 px/thread
  aggregate_kernel<<<(NPIX / 4 * 48) / 256, 256, 0, stream>>>(v, attn, y);

  // 3. out = y @ Wtp^T + b_proj (fp32 out)
  gemm_proj_kernel<<<dim3(NPIX / 64, 2), 256, 0, stream>>>(
      y, Wtp_frag, b_proj, out);
}

// Round 18
// 121.981 us; speedup vs baseline: 1.0213x; 1.0213x over previous
//
#include <hip/hip_runtime.h>
#include <math.h>

#define NPIX 50176      // 16*56*56
#define CDIM 384
#define HEADS 6
#define NLOGIT 54       // HEADS*9
#define HH 56
#define WW 56
#define KSTEPS 12       // CDIM/32
#define TSTEPS 6        // CDIM/64 (BK=64 outer steps)
#define NCH_V 28        // total fragment chunks (448 cols / 16)
#define NCH_P 24        // proj fragment chunks (384 cols / 16)

typedef __attribute__((ext_vector_type(8))) __bf16 bf16x8;
typedef __attribute__((ext_vector_type(4))) float f32x4;

__device__ __forceinline__ void glds16(const void* g, void* l) {
  __builtin_amdgcn_global_load_lds(
      (const __attribute__((address_space(1))) unsigned int*)g,
      (__attribute__((address_space(3))) unsigned int*)l, 16, 0, 0);
}

// ---------------------------------------------------------------------------
// Prep: fragment-major weights (unchanged, proven).
// ---------------------------------------------------------------------------
__global__ __launch_bounds__(256) void prep_kernel(
    const float* __restrict__ W_v, const float* __restrict__ W_proj,
    const float* __restrict__ W_attn, const float* __restrict__ b_attn,
    __bf16* __restrict__ Wcat_frag, __bf16* __restrict__ Wtp_frag,
    float* __restrict__ bpad) {
  const int gid = blockIdx.x * 256 + threadIdx.x;
  const int NV = KSTEPS * NCH_V * 64;   // 21504
  const int NP = KSTEPS * NCH_P * 64;   // 18432
  if (gid < NV) {
    const int ks   = gid / (NCH_V * 64);
    const int rem  = gid % (NCH_V * 64);
    const int ni   = rem >> 6;
    const int lane = rem & 63;
    const int n  = ni * 16 + (lane & 15);
    const int kb = ks * 32 + (lane >> 4) * 8;
    bf16x8 o;
    #pragma unroll
    for (int q = 0; q < 8; ++q) {
      const int k = kb + q;
      float val;
      if (n < CDIM) val = W_v[k * CDIM + n];
      else {
        const int nn = n - CDIM;
        val = (nn < NLOGIT) ? W_attn[k * NLOGIT + nn] : 0.f;
      }
      o[q] = (__bf16)val;
    }
    *(bf16x8*)&Wcat_frag[(size_t)gid * 8] = o;
  } else if (gid < NV + NP) {
    const int r    = gid - NV;
    const int ks   = r / (NCH_P * 64);
    const int rem  = r % (NCH_P * 64);
    const int ni   = rem >> 6;
    const int lane = rem & 63;
    const int n  = ni * 16 + (lane & 15);
    const int kb = ks * 32 + (lane >> 4) * 8;
    bf16x8 o;
    #pragma unroll
    for (int q = 0; q < 8; ++q) o[q] = (__bf16)W_proj[(kb + q) * CDIM + n];
    *(bf16x8*)&Wtp_frag[(size_t)r * 8] = o;
  } else if (gid < NV + NP + 64) {
    const int n = gid - NV - NP;
    bpad[n] = (n < NLOGIT) ? b_attn[n] : 0.f;
  }
}

// ---------------------------------------------------------------------------
// Cast x fp32 -> bf16, 16 elements / thread. Pure streaming (~19us).
// ---------------------------------------------------------------------------
__global__ __launch_bounds__(256) void cast_x_kernel(
    const float* __restrict__ x, __bf16* __restrict__ xb) {
  const size_t i = (size_t)blockIdx.x * 256 + threadIdx.x;
  const float4* src = (const float4*)x + i * 4;
  const float4 f0 = src[0];
  const float4 f1 = src[1];
  const float4 f2 = src[2];
  const float4 f3 = src[3];
  bf16x8 o0, o1;
  o0[0] = (__bf16)f0.x; o0[1] = (__bf16)f0.y; o0[2] = (__bf16)f0.z; o0[3] = (__bf16)f0.w;
  o0[4] = (__bf16)f1.x; o0[5] = (__bf16)f1.y; o0[6] = (__bf16)f1.z; o0[7] = (__bf16)f1.w;
  o1[0] = (__bf16)f2.x; o1[1] = (__bf16)f2.y; o1[2] = (__bf16)f2.z; o1[3] = (__bf16)f2.w;
  o1[4] = (__bf16)f3.x; o1[5] = (__bf16)f3.y; o1[6] = (__bf16)f3.z; o1[7] = (__bf16)f3.w;
  ((bf16x8*)xb)[i * 2]     = o0;
  ((bf16x8*)xb)[i * 2 + 1] = o1;
}

// ---------------------------------------------------------------------------
// GEMM body — BK=64 variant of the proven plain-__syncthreads schedule:
// 6 outer steps, each stages TWO k-subtiles (2xCPW glds16) and runs 2xNCH
// MFMAs -> half the barrier-drain stalls of the BK=32 version. Same sync
// class (full drain per step, double buffer) = race-free.
// ---------------------------------------------------------------------------
template <int NCH, int STRIDE, int NBASE, bool LOGIT, bool F32OUT>
__device__ __forceinline__ void gemm_body(
    const __bf16* __restrict__ A, const __bf16* __restrict__ Wf,
    const float* __restrict__ bias, void* __restrict__ out,
    const float* __restrict__ bpad, float* __restrict__ attn,
    __bf16* Bs, int bm, int tid) {
  constexpr int CPW  = NCH / 4;         // chunks per wave per subtile
  constexpr int BUFE = NCH * 1024;      // elements per buffer (2 subtiles)
  const int wave = tid >> 6;
  const int lane = tid & 63;
  const int frow = lane & 15;
  const int fk8  = (lane >> 4) * 8;
  const int arow = bm + wave * 16 + frow;
  const __bf16* xrow = A + (size_t)arow * CDIM + fk8;

  f32x4 acc[NCH] = {};

  // prologue: stage t=0 (ks 0,1) -> buf0; load A pair 0
  #pragma unroll
  for (int c = 0; c < CPW; ++c) {
    const int chunk = wave * CPW + c;
    glds16(Wf + ((size_t)(NBASE + chunk) * 64 + lane) * 8,
           Bs + chunk * 512);
    glds16(Wf + ((size_t)(STRIDE + NBASE + chunk) * 64 + lane) * 8,
           Bs + NCH * 512 + chunk * 512);
  }
  bf16x8 a0 = *(const bf16x8*)xrow;
  bf16x8 a1 = *(const bf16x8*)(xrow + 32);
  __syncthreads();

  int buf = 0;
  #pragma unroll
  for (int t = 0; t < TSTEPS; ++t) {
    if (t + 1 < TSTEPS) {
      __bf16* dst = Bs + (buf ^ 1) * BUFE;
      #pragma unroll
      for (int c = 0; c < CPW; ++c) {
        const int chunk = wave * CPW + c;
        glds16(Wf + ((size_t)((2 * t + 2) * STRIDE + NBASE + chunk) * 64 + lane) * 8,
               dst + chunk * 512);
        glds16(Wf + ((size_t)((2 * t + 3) * STRIDE + NBASE + chunk) * 64 + lane) * 8,
               dst + NCH * 512 + chunk * 512);
      }
    }
    bf16x8 a0n, a1n;
    if (t + 1 < TSTEPS) {
      a0n = *(const bf16x8*)(xrow + (2 * t + 2) * 32);
      a1n = *(const bf16x8*)(xrow + (2 * t + 3) * 32);
    }

    const __bf16* Bc = Bs + buf * BUFE;
    #pragma unroll
    for (int ni = 0; ni < NCH; ++ni) {
      const bf16x8 b0 = *(const bf16x8*)&Bc[(ni * 64 + lane) * 8];
      acc[ni] = __builtin_amdgcn_mfma_f32_16x16x32_bf16(a0, b0, acc[ni], 0, 0, 0);
    }
    #pragma unroll
    for (int ni = 0; ni < NCH; ++ni) {
      const bf16x8 b1 = *(const bf16x8*)&Bc[NCH * 512 + (ni * 64 + lane) * 8];
      acc[ni] = __builtin_amdgcn_mfma_f32_16x16x32_bf16(a1, b1, acc[ni], 0, 0, 0);
    }
    __syncthreads();
    buf ^= 1;
    a0 = a0n; a1 = a1n;
  }

  const int orow = (lane >> 4) * 4;
  constexpr int NV = LOGIT ? NCH - 4 : NCH;

  #pragma unroll
  for (int ni = 0; ni < NV; ++ni) {
    const int n = (NBASE + ni) * 16 + frow;
    const float bvl = bias[n];
    #pragma unroll
    for (int r = 0; r < 4; ++r) {
      const int m = bm + wave * 16 + orow + r;
      const float val = acc[ni][r] + bvl;
      if constexpr (F32OUT)
        ((float*)out)[(size_t)m * CDIM + n] = val;
      else
        ((__bf16*)out)[(size_t)m * CDIM + n] = (__bf16)val;
    }
  }

  if constexpr (LOGIT) {
    float (*Ls)[68] = (float(*)[68])Bs;
    __syncthreads();   // all waves done reading Bs before overlay
    float bvl[4];
    #pragma unroll
    for (int ni = 0; ni < 4; ++ni) bvl[ni] = bpad[ni * 16 + frow];
    #pragma unroll
    for (int ni = 0; ni < 4; ++ni)
      #pragma unroll
      for (int r = 0; r < 4; ++r)
        Ls[wave * 16 + orow + r][ni * 16 + frow] = acc[NV + ni][r] + bvl[ni];
    __syncthreads();

    #pragma unroll
    for (int it = 0; it < 2; ++it) {
      const int task = it * 256 + tid;
      if (task < 64 * HEADS) {
        const int pl = task / HEADS;
        const int h  = task % HEADS;
        const float* row = &Ls[pl][h * 9];
        float m = row[0];
        #pragma unroll
        for (int w = 1; w < 9; ++w) m = fmaxf(m, row[w]);
        float e[9], s = 0.f;
        #pragma unroll
        for (int w = 0; w < 9; ++w) { e[w] = __expf(row[w] - m); s += e[w]; }
        const float inv = 1.f / s;
        float* op = &attn[(size_t)(bm + pl) * NLOGIT + h * 9];
        #pragma unroll
        for (int w = 0; w < 9; ++w) op[w] = e[w] * inv;
      }
    }
  }
}

// ---------------------------------------------------------------------------
// Merged v + logit GEMM: grid (NPIX/64, 3).
//   by=0: chunks 0..11  (v cols 0..191)
//   by=1: chunks 12..23 (v cols 192..383)
//   by=2: chunks 24..27 (logit cols) -> softmax -> attn
// ---------------------------------------------------------------------------
__global__ __launch_bounds__(256) void gemm_v_logit_kernel(
    const __bf16* __restrict__ xb, const __bf16* __restrict__ Wcat_frag,
    const float* __restrict__ b_v, __bf16* __restrict__ v,
    const float* __restrict__ bpad, float* __restrict__ attn) {
  __shared__ __bf16 Bs[2 * 12 * 1024];   // 48KB (by=2 uses 16KB; Ls 17.4KB)
  const int bm = blockIdx.x * 64;
  if (blockIdx.y == 0)
    gemm_body<12, NCH_V, 0, false, false>(
        xb, Wcat_frag, b_v, v, bpad, attn, Bs, bm, threadIdx.x);
  else if (blockIdx.y == 1)
    gemm_body<12, NCH_V, 12, false, false>(
        xb, Wcat_frag, b_v, v, bpad, attn, Bs, bm, threadIdx.x);
  else
    gemm_body<4, NCH_V, 24, true, false>(
        xb, Wcat_frag, b_v, v, bpad, attn, Bs, bm, threadIdx.x);
}

// ---------------------------------------------------------------------------
// Proj GEMM: grid (NPIX/64, 2), 12 chunks each, BK=64 body. Out fp32.
// ---------------------------------------------------------------------------
__global__ __launch_bounds__(256) void gemm_proj_kernel(
    const __bf16* __restrict__ Y, const __bf16* __restrict__ Wtp_frag,
    const float* __restrict__ bias, float* __restrict__ Out) {
  __shared__ __bf16 Bs[2 * 12 * 1024];   // 48KB
  const int bm = blockIdx.x * 64;
  if (blockIdx.y == 0)
    gemm_body<12, NCH_P, 0, false, true>(
        Y, Wtp_frag, bias, Out, nullptr, nullptr, Bs, bm, threadIdx.x);
  else
    gemm_body<12, NCH_P, 12, false, true>(
        Y, Wtp_frag, bias, Out, nullptr, nullptr, Bs, bm, threadIdx.x);
}

// ---------------------------------------------------------------------------
// Window aggregation, 4 vertically-adjacent pixels per thread (unchanged).
// ---------------------------------------------------------------------------
__global__ __launch_bounds__(256) void aggregate_kernel(
    const __bf16* __restrict__ v, const float* __restrict__ attn,
    __bf16* __restrict__ y) {
  const int idx = blockIdx.x * 256 + threadIdx.x;  // NPIX/4 * 48 = 602112
  const int cg = idx % 48;
  const int pg = idx / 48;
  const int c  = cg * 8;
  const int b  = pg / ((HH / 4) * WW);
  const int r2 = pg % ((HH / 4) * WW);
  const int i0 = (r2 / WW) * 4;
  const int j  = r2 % WW;
  const int head = c >> 6;

  const int pbase = (b * HH + i0) * WW + j;
  float aw[4][9];
  #pragma unroll
  for (int p = 0; p < 4; ++p) {
    const float* ap = attn + (size_t)(pbase + p * WW) * NLOGIT + head * 9;
    #pragma unroll
    for (int w = 0; w < 9; ++w) aw[p][w] = ap[w];
  }

  const bool j0ok = (j > 0), j2ok = (j < WW - 1);
  float acc[4][8] = {};

  #pragma unroll
  for (int li = 0; li < 6; ++li) {
    const int ii = i0 - 1 + li;
    if (ii < 0 || ii >= HH) continue;
    const __bf16* vrow = v + ((size_t)(b * HH + ii) * WW + j) * CDIM + c;
    float ch[3][8];
    #pragma unroll
    for (int kj = 0; kj < 3; ++kj) {
      const bool ok = (kj == 0) ? j0ok : (kj == 2) ? j2ok : true;
      if (ok) {
        const bf16x8 vv = *(const bf16x8*)(vrow + (kj - 1) * CDIM);
        #pragma unroll
        for (int q = 0; q < 8; ++q) ch[kj][q] = (float)vv[q];
      } else {
        #pragma unroll
        for (int q = 0; q < 8; ++q) ch[kj][q] = 0.f;
      }
    }
    #pragma unroll
    for (int p = 0; p < 4; ++p) {
      const int ki = li - p;
      if (ki < 0 || ki > 2) continue;
      #pragma unroll
      for (int kj = 0; kj < 3; ++kj) {
        const float w = aw[p][ki * 3 + kj];
        #pragma unroll
        for (int q = 0; q < 8; ++q) acc[p][q] += w * ch[kj][q];
      }
    }
  }

  #pragma unroll
  for (int p = 0; p < 4; ++p) {
    bf16x8 o;
    #pragma unroll
    for (int q = 0; q < 8; ++q) o[q] = (__bf16)acc[p][q];
    *(bf16x8*)&y[(size_t)(pbase + p * WW) * CDIM + c] = o;
  }
}

// ---------------------------------------------------------------------------
extern "C" void kernel_launch(void* const* d_in, const int* in_sizes, int n_in,
                              void* d_out, int out_size, void* d_ws,
                              size_t ws_size, hipStream_t stream) {
  const float* x      = (const float*)d_in[0];
  const float* W_attn = (const float*)d_in[1];
  const float* b_attn = (const float*)d_in[2];
  const float* W_v    = (const float*)d_in[3];
  const float* b_v    = (const float*)d_in[4];
  const float* W_proj = (const float*)d_in[5];
  const float* b_proj = (const float*)d_in[6];
  float* out = (float*)d_out;

  char* w = (char*)d_ws;
  __bf16* xb   = (__bf16*)w;  w += (size_t)NPIX * CDIM * 2;   // 38.5MB
  __bf16* v    = (__bf16*)w;  w += (size_t)NPIX * CDIM * 2;   // 38.5MB
  __bf16* y    = (__bf16*)w;  w += (size_t)NPIX * CDIM * 2;   // 38.5MB
  float*  attn = (float*)w;   w += (size_t)NPIX * NLOGIT * 4; // 10.8MB
  __bf16* Wcat_frag = (__bf16*)w;  w += (size_t)(NCH_V * 16) * CDIM * 2;
  __bf16* Wtp_frag  = (__bf16*)w;  w += (size_t)CDIM * CDIM * 2;
  float*  bpad = (float*)w;   w += 64 * 4;

  // prep: fragment-major weights
  const int prep_n = KSTEPS * NCH_V * 64 + KSTEPS * NCH_P * 64 + 64;
  prep_kernel<<<(prep_n + 255) / 256, 256, 0, stream>>>(
      W_v, W_proj, W_attn, b_attn, Wcat_frag, Wtp_frag, bpad);

  // 0. x -> bf16 (streaming)
  cast_x_kernel<<<(NPIX * CDIM / 16) / 256, 256, 0, stream>>>(x, xb);

  // 1. merged v-GEMM + logits/softmax (BK=64, 3 panels)
  gemm_v_logit_kernel<<<dim3(NPIX / 64, 3), 256, 0, stream>>>(
      xb, Wcat_frag, b_v, v, bpad, attn);

  // 2. window aggregation -> y (bf16), 4 px/thread
  aggregate_kernel<<<(NPIX / 4 * 48) / 256, 256, 0, stream>>>(v, attn, y);

  // 3. out = y @ Wtp^T + b_proj (fp32 out), BK=64
  gemm_proj_kernel<<<dim3(NPIX / 64, 2), 256, 0, stream>>>(
      y, Wtp_frag, b_proj, out);
}

// Round 19
// 118.648 us; speedup vs baseline: 1.0500x; 1.0281x over previous
//
#include <hip/hip_runtime.h>
#include <math.h>

#define NPIX 50176      // 16*56*56
#define CDIM 384
#define HEADS 6
#define NLOGIT 54       // HEADS*9
#define HH 56
#define WW 56
#define KSTEPS 12       // CDIM/32
#define NCH_V 28        // total fragment chunks (448 cols / 16)
#define NCH_P 24        // proj fragment chunks (384 cols / 16)

typedef __attribute__((ext_vector_type(8))) __bf16 bf16x8;
typedef __attribute__((ext_vector_type(4))) float f32x4;

__device__ __forceinline__ void glds16(const void* g, void* l) {
  __builtin_amdgcn_global_load_lds(
      (const __attribute__((address_space(1))) unsigned int*)g,
      (__attribute__((address_space(3))) unsigned int*)l, 16, 0, 0);
}

// ---------------------------------------------------------------------------
// Prep: fragment-major weights (unchanged, proven).
// ---------------------------------------------------------------------------
__global__ __launch_bounds__(256) void prep_kernel(
    const float* __restrict__ W_v, const float* __restrict__ W_proj,
    const float* __restrict__ W_attn, const float* __restrict__ b_attn,
    __bf16* __restrict__ Wcat_frag, __bf16* __restrict__ Wtp_frag,
    float* __restrict__ bpad) {
  const int gid = blockIdx.x * 256 + threadIdx.x;
  const int NV = KSTEPS * NCH_V * 64;   // 21504
  const int NP = KSTEPS * NCH_P * 64;   // 18432
  if (gid < NV) {
    const int ks   = gid / (NCH_V * 64);
    const int rem  = gid % (NCH_V * 64);
    const int ni   = rem >> 6;
    const int lane = rem & 63;
    const int n  = ni * 16 + (lane & 15);
    const int kb = ks * 32 + (lane >> 4) * 8;
    bf16x8 o;
    #pragma unroll
    for (int q = 0; q < 8; ++q) {
      const int k = kb + q;
      float val;
      if (n < CDIM) val = W_v[k * CDIM + n];
      else {
        const int nn = n - CDIM;
        val = (nn < NLOGIT) ? W_attn[k * NLOGIT + nn] : 0.f;
      }
      o[q] = (__bf16)val;
    }
    *(bf16x8*)&Wcat_frag[(size_t)gid * 8] = o;
  } else if (gid < NV + NP) {
    const int r    = gid - NV;
    const int ks   = r / (NCH_P * 64);
    const int rem  = r % (NCH_P * 64);
    const int ni   = rem >> 6;
    const int lane = rem & 63;
    const int n  = ni * 16 + (lane & 15);
    const int kb = ks * 32 + (lane >> 4) * 8;
    bf16x8 o;
    #pragma unroll
    for (int q = 0; q < 8; ++q) o[q] = (__bf16)W_proj[(kb + q) * CDIM + n];
    *(bf16x8*)&Wtp_frag[(size_t)r * 8] = o;
  } else if (gid < NV + NP + 64) {
    const int n = gid - NV - NP;
    bpad[n] = (n < NLOGIT) ? b_attn[n] : 0.f;
  }
}

// ---------------------------------------------------------------------------
// GEMM body — proven plain-__syncthreads BK=32 double-buffer schedule.
// A per-lane from global, fp32 (2x float4 + cvt) or bf16x8, 1-step prefetch.
// B fragment-major via glds16 (conflict-free).
// ---------------------------------------------------------------------------
template <int NCH, int STRIDE, int NBASE, bool LOGIT, bool F32OUT, bool F32IN>
__device__ __forceinline__ void gemm_body(
    const void* __restrict__ Ain, const __bf16* __restrict__ Wf,
    const float* __restrict__ bias, void* __restrict__ out,
    const float* __restrict__ bpad, float* __restrict__ attn,
    __bf16* Bs, int bm, int tid) {
  constexpr int CPW = NCH / 4;          // chunks per wave (uniform in block)
  const int wave = tid >> 6;
  const int lane = tid & 63;
  const int frow = lane & 15;
  const int fk8  = (lane >> 4) * 8;
  const int arow = bm + wave * 16 + frow;
  const float*  xrf = (const float*)Ain  + (size_t)arow * CDIM + fk8;
  const __bf16* xrb = (const __bf16*)Ain + (size_t)arow * CDIM + fk8;

  f32x4 acc[NCH] = {};

  // prologue: stage(0) -> buf0, prefetch A(0)
  #pragma unroll
  for (int c = 0; c < CPW; ++c) {
    const int chunk = wave * CPW + c;
    glds16(Wf + ((size_t)(NBASE + chunk) * 64 + lane) * 8, Bs + chunk * 512);
  }
  float4 pf0, pf1;
  bf16x8 pb;
  if constexpr (F32IN) {
    pf0 = *(const float4*)xrf;
    pf1 = *(const float4*)(xrf + 4);
  } else {
    pb = *(const bf16x8*)xrb;
  }
  __syncthreads();

  int buf = 0;
  for (int ks = 0; ks < KSTEPS; ++ks) {
    // issue next-step stage into the other buffer (overlaps MFMA below,
    // drained by the end-of-iteration __syncthreads)
    if (ks + 1 < KSTEPS) {
      __bf16* dst = Bs + (buf ^ 1) * NCH * 512;
      #pragma unroll
      for (int c = 0; c < CPW; ++c) {
        const int chunk = wave * CPW + c;
        glds16(Wf + ((size_t)((ks + 1) * STRIDE + NBASE + chunk) * 64 + lane) * 8,
               dst + chunk * 512);
      }
    }
    // materialize A(ks); prefetch A(ks+1)
    bf16x8 a;
    if constexpr (F32IN) {
      a[0] = (__bf16)pf0.x; a[1] = (__bf16)pf0.y; a[2] = (__bf16)pf0.z; a[3] = (__bf16)pf0.w;
      a[4] = (__bf16)pf1.x; a[5] = (__bf16)pf1.y; a[6] = (__bf16)pf1.z; a[7] = (__bf16)pf1.w;
    } else {
      a = pb;
    }
    if (ks + 1 < KSTEPS) {
      if constexpr (F32IN) {
        pf0 = *(const float4*)(xrf + (ks + 1) * 32);
        pf1 = *(const float4*)(xrf + (ks + 1) * 32 + 4);
      } else {
        pb = *(const bf16x8*)(xrb + (ks + 1) * 32);
      }
    }

    const __bf16* Bc = Bs + buf * NCH * 512;
    #pragma unroll
    for (int ni = 0; ni < NCH; ++ni) {
      const bf16x8 b = *(const bf16x8*)&Bc[(ni * 64 + lane) * 8];
      acc[ni] = __builtin_amdgcn_mfma_f32_16x16x32_bf16(a, b, acc[ni], 0, 0, 0);
    }
    __syncthreads();
    buf ^= 1;
  }

  const int orow = (lane >> 4) * 4;
  constexpr int NV = LOGIT ? NCH - 4 : NCH;

  #pragma unroll
  for (int ni = 0; ni < NV; ++ni) {
    const int n = (NBASE + ni) * 16 + frow;
    const float bvl = bias[n];
    #pragma unroll
    for (int r = 0; r < 4; ++r) {
      const int m = bm + wave * 16 + orow + r;
      const float val = acc[ni][r] + bvl;
      if constexpr (F32OUT)
        ((float*)out)[(size_t)m * CDIM + n] = val;
      else
        ((__bf16*)out)[(size_t)m * CDIM + n] = (__bf16)val;
    }
  }

  if constexpr (LOGIT) {
    float (*Ls)[68] = (float(*)[68])Bs;
    __syncthreads();   // all waves done reading Bs before overlay
    float bvl[4];
    #pragma unroll
    for (int ni = 0; ni < 4; ++ni) bvl[ni] = bpad[ni * 16 + frow];
    #pragma unroll
    for (int ni = 0; ni < 4; ++ni)
      #pragma unroll
      for (int r = 0; r < 4; ++r)
        Ls[wave * 16 + orow + r][ni * 16 + frow] = acc[NV + ni][r] + bvl[ni];
    __syncthreads();

    #pragma unroll
    for (int it = 0; it < 2; ++it) {
      const int task = it * 256 + tid;
      if (task < 64 * HEADS) {
        const int pl = task / HEADS;
        const int h  = task % HEADS;
        const float* row = &Ls[pl][h * 9];
        float m = row[0];
        #pragma unroll
        for (int w = 1; w < 9; ++w) m = fmaxf(m, row[w]);
        float e[9], s = 0.f;
        #pragma unroll
        for (int w = 0; w < 9; ++w) { e[w] = __expf(row[w] - m); s += e[w]; }
        const float inv = 1.f / s;
        float* op = &attn[(size_t)(bm + pl) * NLOGIT + h * 9];
        #pragma unroll
        for (int w = 0; w < 9; ++w) op[w] = e[w] * inv;
      }
    }
  }
}

// ---------------------------------------------------------------------------
// Merged v + logit GEMM, fp32 A direct from x (no cast_x dispatch).
// grid (NPIX/64, 3): by0/by1 = 12-chunk v panels, by2 = 4-chunk logit panel.
// ---------------------------------------------------------------------------
__global__ __launch_bounds__(256) void gemm_v_logit_kernel(
    const float* __restrict__ x, const __bf16* __restrict__ Wcat_frag,
    const float* __restrict__ b_v, __bf16* __restrict__ v,
    const float* __restrict__ bpad, float* __restrict__ attn) {
  __shared__ __bf16 Bs[2 * 12 * 512];   // 24KB (Ls overlay needs 17.4KB)
  const int bm = blockIdx.x * 64;
  if (blockIdx.y == 0)
    gemm_body<12, NCH_V, 0, false, false, true>(
        x, Wcat_frag, b_v, v, bpad, attn, Bs, bm, threadIdx.x);
  else if (blockIdx.y == 1)
    gemm_body<12, NCH_V, 12, false, false, true>(
        x, Wcat_frag, b_v, v, bpad, attn, Bs, bm, threadIdx.x);
  else
    gemm_body<4, NCH_V, 24, true, false, true>(
        x, Wcat_frag, b_v, v, bpad, attn, Bs, bm, threadIdx.x);
}

// ---------------------------------------------------------------------------
// Proj GEMM: grid (NPIX/64, 2), 12 chunks each, bf16 A (proven ~22-25us).
// ---------------------------------------------------------------------------
__global__ __launch_bounds__(256) void gemm_proj_kernel(
    const __bf16* __restrict__ Y, const __bf16* __restrict__ Wtp_frag,
    const float* __restrict__ bias, float* __restrict__ Out) {
  __shared__ __bf16 Bs[2 * 12 * 512];   // 24KB
  const int bm = blockIdx.x * 64;
  if (blockIdx.y == 0)
    gemm_body<12, NCH_P, 0, false, true, false>(
        Y, Wtp_frag, bias, Out, nullptr, nullptr, Bs, bm, threadIdx.x);
  else
    gemm_body<12, NCH_P, 12, false, true, false>(
        Y, Wtp_frag, bias, Out, nullptr, nullptr, Bs, bm, threadIdx.x);
}

// ---------------------------------------------------------------------------
// Window aggregation, 4 vertically-adjacent pixels per thread (unchanged).
// ---------------------------------------------------------------------------
__global__ __launch_bounds__(256) void aggregate_kernel(
    const __bf16* __restrict__ v, const float* __restrict__ attn,
    __bf16* __restrict__ y) {
  const int idx = blockIdx.x * 256 + threadIdx.x;  // NPIX/4 * 48 = 602112
  const int cg = idx % 48;
  const int pg = idx / 48;
  const int c  = cg * 8;
  const int b  = pg / ((HH / 4) * WW);
  const int r2 = pg % ((HH / 4) * WW);
  const int i0 = (r2 / WW) * 4;
  const int j  = r2 % WW;
  const int head = c >> 6;

  const int pbase = (b * HH + i0) * WW + j;
  float aw[4][9];
  #pragma unroll
  for (int p = 0; p < 4; ++p) {
    const float* ap = attn + (size_t)(pbase + p * WW) * NLOGIT + head * 9;
    #pragma unroll
    for (int w = 0; w < 9; ++w) aw[p][w] = ap[w];
  }

  const bool j0ok = (j > 0), j2ok = (j < WW - 1);
  float acc[4][8] = {};

  #pragma unroll
  for (int li = 0; li < 6; ++li) {
    const int ii = i0 - 1 + li;
    if (ii < 0 || ii >= HH) continue;
    const __bf16* vrow = v + ((size_t)(b * HH + ii) * WW + j) * CDIM + c;
    float ch[3][8];
    #pragma unroll
    for (int kj = 0; kj < 3; ++kj) {
      const bool ok = (kj == 0) ? j0ok : (kj == 2) ? j2ok : true;
      if (ok) {
        const bf16x8 vv = *(const bf16x8*)(vrow + (kj - 1) * CDIM);
        #pragma unroll
        for (int q = 0; q < 8; ++q) ch[kj][q] = (float)vv[q];
      } else {
        #pragma unroll
        for (int q = 0; q < 8; ++q) ch[kj][q] = 0.f;
      }
    }
    #pragma unroll
    for (int p = 0; p < 4; ++p) {
      const int ki = li - p;
      if (ki < 0 || ki > 2) continue;
      #pragma unroll
      for (int kj = 0; kj < 3; ++kj) {
        const float w = aw[p][ki * 3 + kj];
        #pragma unroll
        for (int q = 0; q < 8; ++q) acc[p][q] += w * ch[kj][q];
      }
    }
  }

  #pragma unroll
  for (int p = 0; p < 4; ++p) {
    bf16x8 o;
    #pragma unroll
    for (int q = 0; q < 8; ++q) o[q] = (__bf16)acc[p][q];
    *(bf16x8*)&y[(size_t)(pbase + p * WW) * CDIM + c] = o;
  }
}

// ---------------------------------------------------------------------------
extern "C" void kernel_launch(void* const* d_in, const int* in_sizes, int n_in,
                              void* d_out, int out_size, void* d_ws,
                              size_t ws_size, hipStream_t stream) {
  const float* x      = (const float*)d_in[0];
  const float* W_attn = (const float*)d_in[1];
  const float* b_attn = (const float*)d_in[2];
  const float* W_v    = (const float*)d_in[3];
  const float* b_v    = (const float*)d_in[4];
  const float* W_proj = (const float*)d_in[5];
  const float* b_proj = (const float*)d_in[6];
  float* out = (float*)d_out;

  char* w = (char*)d_ws;
  __bf16* v    = (__bf16*)w;  w += (size_t)NPIX * CDIM * 2;   // 38.5MB
  __bf16* y    = (__bf16*)w;  w += (size_t)NPIX * CDIM * 2;   // 38.5MB
  float*  attn = (float*)w;   w += (size_t)NPIX * NLOGIT * 4; // 10.8MB
  __bf16* Wcat_frag = (__bf16*)w;  w += (size_t)(NCH_V * 16) * CDIM * 2;
  __bf16* Wtp_frag  = (__bf16*)w;  w += (size_t)CDIM * CDIM * 2;
  float*  bpad = (float*)w;   w += 64 * 4;

  // prep: fragment-major weights
  const int prep_n = KSTEPS * NCH_V * 64 + KSTEPS * NCH_P * 64 + 64;
  prep_kernel<<<(prep_n + 255) / 256, 256, 0, stream>>>(
      W_v, W_proj, W_attn, b_attn, Wcat_frag, Wtp_frag, bpad);

  // 1. merged v-GEMM + logits/softmax (fp32 A in-kernel; no cast_x pass)
  gemm_v_logit_kernel<<<dim3(NPIX / 64, 3), 256, 0, stream>>>(
      x, Wcat_frag, b_v, v, bpad, attn);

  // 2. window aggregation -> y (bf16), 4 px/thread
  aggregate_kernel<<<(NPIX / 4 * 48) / 256, 256, 0, stream>>>(v, attn, y);

  // 3. out = y @ Wtp^T + b_proj (fp32 out)
  gemm_proj_kernel<<<dim3(NPIX / 64, 2), 256, 0, stream>>>(
      y, Wtp_frag, b_proj, out);
}